// Round 13
// baseline (101.870 us; speedup 1.0000x reference)
//
#include <hip/hip_runtime.h>
#include <hip/hip_bf16.h>

// Problem constants (reference: N,E,H,L = 64,64,768,512; eps=1e-12)
#define Nn 64
#define Ee 64
#define Hh 768
#define Ll 512
#define NEH (Nn * Ee * Hh) // 3145728 state elems
#define NEL (Nn * Ee * Ll) // 2097152 mapping elems

typedef __attribute__((ext_vector_type(8))) short bf16x8; // 8 bf16 = 4 VGPRs (MFMA A/B frag)
typedef __attribute__((ext_vector_type(4))) float f32x4;  // MFMA C/D frag

__device__ __forceinline__ unsigned short f2bf(float x) {
    union { __hip_bfloat16 b; unsigned short u; } cv;
    cv.b = __float2bfloat16(x);
    return cv.u;
}
__device__ __forceinline__ float bf2f(unsigned short u) {
    union { float f; unsigned int i; } v;
    v.i = ((unsigned int)u) << 16;
    return v.f;
}

// ---------------------------------------------------------------------------
// Pre-pass: fp32 -> bf16 convert + transpose, LDS-tiled, both sides coalesced.
//   sT[n][h][e]  (H x E per n)   mT[n][l][e]  (L x E per n)      (R3 form)
// ---------------------------------------------------------------------------
__global__ __launch_bounds__(256) void cvt_transpose(
    const float* __restrict__ state, const float* __restrict__ mapping,
    __hip_bfloat16* __restrict__ sT, __hip_bfloat16* __restrict__ mT)
{
    __shared__ unsigned short lds[64][66]; // [x][e]

    int b = blockIdx.x;
    const float* src;
    __hip_bfloat16* dst;
    int W, x0;
    if (b < Nn * (Hh / 64)) {            // state tiles
        int n = b / (Hh / 64);
        x0 = (b % (Hh / 64)) * 64;
        src = state + (size_t)n * Ee * Hh;
        dst = sT + (size_t)n * Hh * Ee;
        W = Hh;
    } else {                              // mapping tiles
        b -= Nn * (Hh / 64);
        int n = b / (Ll / 64);
        x0 = (b % (Ll / 64)) * 64;
        src = mapping + (size_t)n * Ee * Ll;
        dst = mT + (size_t)n * Ll * Ee;
        W = Ll;
    }

    const int xr = (threadIdx.x & 31) * 2;
    const int er = threadIdx.x >> 5;  // 0..7
#pragma unroll
    for (int i = 0; i < 8; ++i) {
        int e = i * 8 + er;
        float2 v = *reinterpret_cast<const float2*>(src + (size_t)e * W + x0 + xr);
        lds[xr][e]     = f2bf(v.x);
        lds[xr + 1][e] = f2bf(v.y);
    }
    __syncthreads();

    const int e4 = (threadIdx.x & 15) * 4;
    const int xw = threadIdx.x >> 4;   // 0..15
    unsigned short* dsts = reinterpret_cast<unsigned short*>(dst);
#pragma unroll
    for (int i = 0; i < 4; ++i) {
        int x = i * 16 + xw;
        uint2 v;
        v.x = *reinterpret_cast<const unsigned int*>(&lds[x][e4]);
        v.y = *reinterpret_cast<const unsigned int*>(&lds[x][e4 + 2]);
        *reinterpret_cast<uint2*>(dsts + (size_t)(x0 + x) * Ee + e4) = v;
    }
}

// ---------------------------------------------------------------------------
// GRAM PASS: per n compute G[e][e'] = sum_h sb[e,h]*sb[e',h]  (E x E, fp32)
// and S1[e] = sum_h sb[e,h], where sb = bf16(state) with the SAME rounding
// as the main path. Stored as gram[n][65][64], row 64 = S1.
// MFMA 16x16x32, K = h: fragments read 8 contiguous fp32 from state[n][e][h]
// and convert on the fly. G is symmetric => a row/col swap in the D-layout
// write is harmless by construction.
// Grid: 64 blocks (one per n) x 256 threads (wave w = 16-row block of G).
// ---------------------------------------------------------------------------
__global__ __launch_bounds__(256) void gram_pass(
    const float* __restrict__ state,  // [N][E][H]
    float* __restrict__ gram)         // [N][65][64]
{
    const int n    = blockIdx.x;
    const int tid  = threadIdx.x;
    const int w    = tid >> 6;
    const int lane = tid & 63;
    const int g    = lane >> 4;
    const int c    = lane & 15;
    const float* sn = state + (size_t)n * (Ee * Hh);

    // ---------------- G via MFMA ----------------
    f32x4 acc[4];
#pragma unroll
    for (int j = 0; j < 4; ++j) acc[j] = (f32x4){0.f, 0.f, 0.f, 0.f};

#pragma unroll 1
    for (int ks = 0; ks < 24; ++ks) {
        const int h0 = ks * 32 + g * 8;
        // A-frag: rows e = w*16+c (address-runtime w: fine; no runtime reg-index)
        bf16x8 fa;
        {
            const float* p = sn + (size_t)(w * 16 + c) * Hh + h0;
            float4 a = *reinterpret_cast<const float4*>(p);
            float4 b = *reinterpret_cast<const float4*>(p + 4);
            fa[0] = (short)f2bf(a.x); fa[1] = (short)f2bf(a.y);
            fa[2] = (short)f2bf(a.z); fa[3] = (short)f2bf(a.w);
            fa[4] = (short)f2bf(b.x); fa[5] = (short)f2bf(b.y);
            fa[6] = (short)f2bf(b.z); fa[7] = (short)f2bf(b.w);
        }
#pragma unroll
        for (int j = 0; j < 4; ++j) {
            const float* p = sn + (size_t)(j * 16 + c) * Hh + h0;
            float4 a = *reinterpret_cast<const float4*>(p);
            float4 b = *reinterpret_cast<const float4*>(p + 4);
            bf16x8 fb;
            fb[0] = (short)f2bf(a.x); fb[1] = (short)f2bf(a.y);
            fb[2] = (short)f2bf(a.z); fb[3] = (short)f2bf(a.w);
            fb[4] = (short)f2bf(b.x); fb[5] = (short)f2bf(b.y);
            fb[6] = (short)f2bf(b.z); fb[7] = (short)f2bf(b.w);
            acc[j] = __builtin_amdgcn_mfma_f32_16x16x32_bf16(fa, fb, acc[j], 0, 0, 0);
        }
    }
    // D[row][col]: row = g*4+r (e local to block w), col = c (e' local to block j)
    float* Gn = gram + (size_t)n * (65 * 64);
#pragma unroll
    for (int j = 0; j < 4; ++j)
#pragma unroll
        for (int r = 0; r < 4; ++r)
            Gn[(w * 16 + g * 4 + r) * 64 + j * 16 + c] = acc[j][r];

    // ---------------- S1 ----------------
    __shared__ float S1p[64][4];
    {
        const int e  = tid >> 2;
        const int qt = tid & 3;
        const float* p = sn + (size_t)e * Hh + qt * 192;
        float s1 = 0.f;
#pragma unroll
        for (int i = 0; i < 48; ++i) {
            float4 v = *reinterpret_cast<const float4*>(p + i * 4);
            s1 += bf2f(f2bf(v.x)) + bf2f(f2bf(v.y)) + bf2f(f2bf(v.z)) + bf2f(f2bf(v.w));
        }
        S1p[e][qt] = s1;
    }
    __syncthreads();
    if (tid < 64)
        Gn[64 * 64 + tid] = S1p[tid][0] + S1p[tid][1] + S1p[tid][2] + S1p[tid][3];
}

// ---------------------------------------------------------------------------
// QUAD STATS: per (n,l):  mu = (m^T S1)/H,  E[x2] = (m^T G m)/H,
// var = E[x2] - mu^2, rstd = rsqrt(var+eps). m = bf16(mapping[n][:,l]) --
// identical rounding to mT. One wave per 64 l's (lane = l); m[64] in regs
// (static-indexed only: load loop + inner loop fully unrolled; outer-loop
// m[e] is re-LOADED from global to avoid runtime reg indexing -> scratch).
// G row reads are wave-uniform -> scalar loads. t split into 4 partials (ILP).
// ---------------------------------------------------------------------------
__global__ __launch_bounds__(64) void quad_stats(
    const float* __restrict__ gram,     // [N][65][64]
    const float* __restrict__ mapping,  // [N][E][L] fp32 original
    float2* __restrict__ stats)         // [N*L] = (mu, rstd)
{
    const int b = blockIdx.x;                 // 0..511
    const int n = b >> 3;
    const int l = ((b & 7) << 6) | threadIdx.x;
    const float* mp = mapping + (size_t)n * (Ee * Ll) + l;

    float m[64];
#pragma unroll
    for (int e = 0; e < 64; ++e)
        m[e] = bf2f(f2bf(mp[(size_t)e * Ll]));

    const float* G = gram + (size_t)n * (65 * 64);
    float quad = 0.f;
#pragma unroll 1
    for (int e = 0; e < 64; ++e) {
        const float me = bf2f(f2bf(mp[(size_t)e * Ll]));  // reload: keeps m[] static-indexed
        const float* Ge = G + e * 64;
        float t0 = 0.f, t1 = 0.f, t2 = 0.f, t3 = 0.f;
#pragma unroll
        for (int e2 = 0; e2 < 64; e2 += 4) {
            t0 = fmaf(Ge[e2 + 0], m[e2 + 0], t0);
            t1 = fmaf(Ge[e2 + 1], m[e2 + 1], t1);
            t2 = fmaf(Ge[e2 + 2], m[e2 + 2], t2);
            t3 = fmaf(Ge[e2 + 3], m[e2 + 3], t3);
        }
        quad = fmaf(me, (t0 + t1) + (t2 + t3), quad);
    }
    float mus = 0.f;
    const float* S1 = G + 64 * 64;
#pragma unroll
    for (int e2 = 0; e2 < 64; ++e2)
        mus = fmaf(S1[e2], m[e2], mus);

    const float mu  = mus * (1.f / Hh);
    const float var = fmaxf(quad * (1.f / Hh) - mu * mu, 0.f);
    stats[n * Ll + l] = make_float2(mu, rsqrtf(var + 1e-12f));
}

// ---------------------------------------------------------------------------
// MAIN PASS (R11's gemm_store, verbatim): mu/rstd precomputed, so each 16x16
// tile is normalized and stored IMMEDIATELY after its 2 MFMAs. No LDS, no
// barriers, no retained accumulator => low regs, high occupancy, stores
// spread uniformly through the t-loop (unroll 1).
// ---------------------------------------------------------------------------
__global__ __launch_bounds__(256) void gemm_store(
    const __hip_bfloat16* __restrict__ sT, // [N][H][E]
    const __hip_bfloat16* __restrict__ mT, // [N][L][E]
    const float2* __restrict__ stats,      // [N*L] = (mu, rstd)
    const float* __restrict__ gamma,
    const float* __restrict__ beta,
    float* __restrict__ out)               // [N][L][H]
{
    const int p    = blockIdx.x;
    const int n    = ((p >> 7) << 3) | (p & 7);
    const int l0   = ((p >> 3) & 15) << 5; // 32 rows per tile
    const int tid  = threadIdx.x;
    const int w    = tid >> 6;
    const int lane = tid & 63;
    const int g    = lane >> 4;
    const int c    = lane & 15;

    bf16x8 b0[2], b1[2];
    float2 st[2];
    float* orow[2];
#pragma unroll
    for (int u = 0; u < 2; ++u) {
        const int l = l0 + u * 16 + c;
        const __hip_bfloat16* Brow = mT + (size_t)(n * Ll + l) * Ee + g * 8;
        b0[u] = *reinterpret_cast<const bf16x8*>(Brow);
        b1[u] = *reinterpret_cast<const bf16x8*>(Brow + 32);
        st[u] = stats[n * Ll + l];
        orow[u] = out + (size_t)(n * Ll + l) * Hh;
    }

    const __hip_bfloat16* Abase = sT + (size_t)(n * Hh + w * 192 + c) * Ee + g * 8;
#pragma unroll 1
    for (int t = 0; t < 12; ++t) {
        const __hip_bfloat16* ap = Abase + (size_t)t * 16 * Ee;
        bf16x8 a0 = *reinterpret_cast<const bf16x8*>(ap);
        bf16x8 a1 = *reinterpret_cast<const bf16x8*>(ap + 32);

        const int hb = w * 192 + t * 16 + g * 4;
        f32x4 gm = *reinterpret_cast<const f32x4*>(gamma + hb);
        f32x4 bt = *reinterpret_cast<const f32x4*>(beta + hb);

#pragma unroll
        for (int u = 0; u < 2; ++u) {
            f32x4 acc = (f32x4){0.f, 0.f, 0.f, 0.f};
            acc = __builtin_amdgcn_mfma_f32_16x16x32_bf16(a0, b0[u], acc, 0, 0, 0);
            acc = __builtin_amdgcn_mfma_f32_16x16x32_bf16(a1, b1[u], acc, 0, 0, 0);
            f32x4 v;
#pragma unroll
            for (int r = 0; r < 4; ++r)
                v[r] = (acc[r] - st[u].x) * st[u].y * gm[r] + bt[r];
            *reinterpret_cast<f32x4*>(orow[u] + hb) = v;
        }
    }
}

extern "C" void kernel_launch(void* const* d_in, const int* in_sizes, int n_in,
                              void* d_out, int out_size, void* d_ws, size_t ws_size,
                              hipStream_t stream)
{
    const float* state   = (const float*)d_in[0]; // (N,E,H)
    const float* mapping = (const float*)d_in[1]; // (N,E,L)
    const float* gamma   = (const float*)d_in[2]; // (H,)
    const float* beta    = (const float*)d_in[3]; // (H,)
    float* out           = (float*)d_out;         // (N,L,H)

    __hip_bfloat16* sT = (__hip_bfloat16*)d_ws;            // NEH bf16
    __hip_bfloat16* mT = sT + NEH;                         // NEL bf16
    float2* stats      = (float2*)((char*)d_ws + (size_t)(NEH + NEL) * 2); // N*L float2
    float*  gram       = (float*)((char*)stats + (size_t)Nn * Ll * sizeof(float2)); // N*65*64 f32
    // total ws use ~11.8 MB

    const int tiles = Nn * (Hh / 64) + Nn * (Ll / 64); // 1280
    cvt_transpose<<<tiles, 256, 0, stream>>>(state, mapping, sT, mT);
    gram_pass<<<Nn, 256, 0, stream>>>(state, gram);
    quad_stats<<<Nn * (Ll / 64), 64, 0, stream>>>(gram, mapping, stats);
    gemm_store<<<Nn * (Ll / 32), 256, 0, stream>>>(sT, mT, stats, gamma, beta, out);
}